// Round 7
// baseline (417.912 us; speedup 1.0000x reference)
//
#include <hip/hip_runtime.h>
#include <math.h>

#define B_  8
#define R_  64
#define C_  256
#define NH_ 8
#define N_  4096
#define HD_ 32
#define TT_ 16          // tokens per LDS tile in kernelNB
#define LDP_ 260        // padded row stride (260%32==4 -> conflict-free f4 writes)

__device__ __forceinline__ float softplus_rcp(float s) {
    return 1.f / __logf(1.f + __expf(s));     // 1/softplus, fast intrinsics
}

// ---------------------------------------------------------------------------
// Kernel NB: fused norm + kv aggregation. Block = 64 tokens (4 tiles of 16) x
// full C. Per tile: load q,k,pos; per-token 256-ch norms via 16-lane shuffle
// (4 tokens/wave); write qs_arr; build kfin = kv^3*ksn and v in LDS; then
// thread (h=t>>5, c=t&31) accumulates kv[c][*] for its head over the tile
// (k_s read conflict-free, v_s read broadcast). atomicAdd epilogue.
// Replaces R6's kernelN+kernelB2: k+pos read once instead of twice.
// ---------------------------------------------------------------------------
__global__ __launch_bounds__(256) void kernelNB(
        const float* __restrict__ qkv, const float* __restrict__ pos,
        const float* __restrict__ scale,
        float* __restrict__ qs_arr,
        float* __restrict__ kv_ws, float* __restrict__ ksum_ws) {
    __shared__ float k_s[TT_][LDP_];
    __shared__ float v_s[TT_][LDP_];
    __shared__ float rsc_s[C_];
    const int t     = threadIdx.x;
    const int b     = blockIdx.x >> 6;     // grid 512 = 8 b x 64 chunks
    const int chunk = blockIdx.x & 63;
    const int h  = t >> 5, cc = t & 31;    // accumulation role
    const int tk = t >> 4, sub = t & 15;   // load/norm role (16 thr/token)

    rsc_s[t] = softplus_rcp(scale[t]);
    __syncthreads();

    float acc[32];
    #pragma unroll
    for (int i = 0; i < 32; i++) acc[i] = 0.f;
    float ksp = 0.f;

    const size_t qbase = (size_t)b * N_ * C_;
    const size_t kbase = (size_t)(B_ + b) * N_ * C_;
    const size_t vbase = (size_t)(2 * B_ + b) * N_ * C_;

    for (int tile = 0; tile < 4; tile++) {
        const int n0  = chunk * 64 + tile * TT_;    // token index within b
        const int tok = n0 + tk;

        // ---- norm pass: 4 f4s of q,k,pos per thread (c4 = sub + 16i) ----
        float kva[16];
        float sq2 = 0.f, sq6 = 0.f, sk2 = 0.f, sk6 = 0.f;
        #pragma unroll
        for (int i = 0; i < 4; i++) {
            const int c0 = (sub + i * 16) * 4;
            const float4 q4 = *(const float4*)(qkv + qbase + (size_t)tok * C_ + c0);
            const float4 k4 = *(const float4*)(qkv + kbase + (size_t)tok * C_ + c0);
            const float4 p4 = *(const float4*)(pos + (size_t)tok * C_ + c0);
            const float qa[4] = {q4.x, q4.y, q4.z, q4.w};
            const float ka[4] = {k4.x, k4.y, k4.z, k4.w};
            const float pa[4] = {p4.x, p4.y, p4.z, p4.w};
            #pragma unroll
            for (int j = 0; j < 4; j++) {
                const float rsc = rsc_s[c0 + j];
                const float qv = (fmaxf(qa[j], 0.f) + 1e-6f) * rsc;
                const float kv = (fmaxf(ka[j] + pa[j], 0.f) + 1e-6f) * rsc;
                sq2 += qv * qv;
                const float q3 = qv * qv * qv;
                sq6 += q3 * q3;
                sk2 += kv * kv;
                const float k3 = kv * kv * kv;
                sk6 += k3 * k3;
                kva[i * 4 + j] = kv;
            }
        }
        #pragma unroll
        for (int m = 1; m < 16; m <<= 1) {
            sq2 += __shfl_xor(sq2, m, 64);
            sq6 += __shfl_xor(sq6, m, 64);
            sk2 += __shfl_xor(sk2, m, 64);
            sk6 += __shfl_xor(sk6, m, 64);
        }
        const float ksn = sqrtf(sk2) * rsqrtf(sk6);
        if (sub == 0)
            qs_arr[b * N_ + tok] = sqrtf(sq2) * rsqrtf(sq6);

        // ---- stage kfin + v into LDS ----
        #pragma unroll
        for (int i = 0; i < 4; i++) {
            const int c0 = (sub + i * 16) * 4;
            float4 o;
            o.x = kva[i*4+0] * kva[i*4+0] * kva[i*4+0] * ksn;
            o.y = kva[i*4+1] * kva[i*4+1] * kva[i*4+1] * ksn;
            o.z = kva[i*4+2] * kva[i*4+2] * kva[i*4+2] * ksn;
            o.w = kva[i*4+3] * kva[i*4+3] * kva[i*4+3] * ksn;
            *(float4*)&k_s[tk][c0] = o;
            *(float4*)&v_s[tk][c0] =
                *(const float4*)(qkv + vbase + (size_t)tok * C_ + c0);
        }
        __syncthreads();

        // ---- accumulate: thread (h, cc) over TT_ tokens ----
        #pragma unroll 4
        for (int nl = 0; nl < TT_; nl++) {
            const float kc = k_s[nl][h * 32 + cc];
            ksp += kc;
            const float* vr = &v_s[nl][h * 32];
            #pragma unroll
            for (int d = 0; d < 32; d++)
                acc[d] = fmaf(kc, vr[d], acc[d]);
        }
        __syncthreads();
    }

    const int bh = b * NH_ + h;
    float* kvdst = kv_ws + (size_t)bh * 1024 + cc * 32;
    #pragma unroll
    for (int d = 0; d < 32; d++)
        atomicAdd(kvdst + d, acc[d]);
    atomicAdd(&ksum_ws[bh * HD_ + cc], ksp);
}

// ---------------------------------------------------------------------------
// Kernel CD2 (R5 version, f32): fused attention epilogue + both depthwise
// convs; out written ONCE via plain float4 stores (L2 write-combines; R4
// showed nontemporal causes 4x write amplification).
// ---------------------------------------------------------------------------
__global__ __launch_bounds__(256) void kernelCD2(
        const float* __restrict__ qkv, const float* __restrict__ qs_arr,
        const float* __restrict__ kv_ws, const float* __restrict__ ksum_ws,
        const float* __restrict__ scale,
        const float* __restrict__ w_v,  const float* __restrict__ b_v,
        const float* __restrict__ w_dwc, const float* __restrict__ b_dwc,
        float* __restrict__ out) {
    __shared__ float v_s[20 * 20 * 32];   // 51.2 KB; reused as conv_s (256*33)
    __shared__ float kv_s[1024];
    __shared__ float ks_s[32];
    __shared__ float rsc_s[32];
    const int t    = threadIdx.x;
    const int tile = blockIdx.x;
    const int h    = blockIdx.y;
    const int b    = blockIdx.z;
    const int ty0  = (tile >> 2) * 16, tx0 = (tile & 3) * 16;
    const int bh   = b * NH_ + h;

    ((float4*)kv_s)[t] = ((const float4*)(kv_ws + (size_t)bh * 1024))[t];
    if (t < 32) {
        ks_s[t]  = ksum_ws[bh * HD_ + t];
        rsc_s[t] = softplus_rcp(scale[h * HD_ + t]);
    }

    const float* vb = qkv + (size_t)2 * B_ * N_ * C_ + (size_t)b * N_ * C_ + h * HD_;
    #pragma unroll
    for (int i = 0; i < 13; i++) {
        const int idx = i * 256 + t;
        if (idx < 3200) {
            const int pix = idx >> 3, d4 = (idx & 7) * 4;
            const int yy = pix / 20, xx = pix - yy * 20;
            const int gy = ty0 + yy - 2, gx = tx0 + xx - 2;
            float4 val = make_float4(0.f, 0.f, 0.f, 0.f);
            if (gy >= 0 && gy < R_ && gx >= 0 && gx < R_)
                val = *(const float4*)(vb + (size_t)(gy * R_ + gx) * C_ + d4);
            *(float4*)&v_s[pix * 32 + d4] = val;
        }
    }

    const int c  = t & 31, pg = t >> 5;
    float wv[9], wd[25];
    {
        const float* wvp = w_v + (size_t)(h * HD_ + c) * 9;
        const float* wdp = w_dwc + (size_t)c * 25;
        #pragma unroll
        for (int i = 0; i < 9; i++)  wv[i] = wvp[i];
        #pragma unroll
        for (int i = 0; i < 25; i++) wd[i] = wdp[i];
    }
    const float bias = b_v[h * HD_ + c] + b_dwc[c];
    __syncthreads();

    // ---- conv phase: thread = (channel c, 2 tile rows), ring window ----
    float res[32];
    #pragma unroll
    for (int r2 = 0; r2 < 2; r2++) {
        const int ty = pg * 2 + r2;
        float win[5][5];
        #pragma unroll
        for (int j = 0; j < 5; j++)
            #pragma unroll
            for (int i = 0; i < 5; i++)
                win[j][i] = v_s[((ty + i) * 20 + j) * 32 + c];
        #pragma unroll
        for (int tx = 0; tx < 16; tx++) {
            float a = bias;
            #pragma unroll
            for (int j = 0; j < 5; j++) {
                const int slot = (tx + j) % 5;
                #pragma unroll
                for (int i = 0; i < 5; i++)
                    a = fmaf(wd[i * 5 + j], win[slot][i], a);
            }
            #pragma unroll
            for (int j = 1; j < 4; j++) {
                const int slot = (tx + j) % 5;
                #pragma unroll
                for (int i = 1; i < 4; i++)
                    a = fmaf(wv[(i - 1) * 3 + (j - 1)], win[slot][i], a);
            }
            res[r2 * 16 + tx] = a;
            if (tx < 15) {
                const int slot = tx % 5;
                #pragma unroll
                for (int i = 0; i < 5; i++)
                    win[slot][i] = v_s[((ty + i) * 20 + (tx + 5)) * 32 + c];
            }
        }
    }
    __syncthreads();
    #pragma unroll
    for (int r2 = 0; r2 < 2; r2++)
        #pragma unroll
        for (int tx = 0; tx < 16; tx++)
            v_s[((pg * 2 + r2) * 16 + tx) * 33 + c] = res[r2 * 16 + tx];
    __syncthreads();

    // ---- attention phase: thread = pixel; q-feature recomputed on the fly ----
    {
        const int tyy = t >> 4, txx = t & 15;
        const int n   = (ty0 + tyy) * R_ + (tx0 + txx);
        const int tok = b * N_ + n;
        float q[32];
        const float4* qsrc = (const float4*)(qkv + (size_t)tok * C_ + h * HD_);
        #pragma unroll
        for (int i = 0; i < 8; i++) ((float4*)q)[i] = qsrc[i];
        const float qs = qs_arr[tok];
        #pragma unroll
        for (int i = 0; i < 32; i++) {
            const float r = (fmaxf(q[i], 0.f) + 1e-6f) * rsc_s[i];
            q[i] = r * r * r * qs;
        }

        float denom = 1e-6f;
        #pragma unroll
        for (int cc = 0; cc < 32; cc++) denom = fmaf(q[cc], ks_s[cc], denom);
        const float z = 1.f / denom;

        float o[32];
        #pragma unroll
        for (int i = 0; i < 32; i++) o[i] = 0.f;
        #pragma unroll
        for (int cc = 0; cc < 32; cc++) {
            const float qc = q[cc];
            #pragma unroll
            for (int d = 0; d < 32; d++)
                o[d] = fmaf(qc, kv_s[cc * 32 + d], o[d]);
        }
        float4* dst = (float4*)(out + (size_t)tok * C_ + h * HD_);
        #pragma unroll
        for (int i = 0; i < 8; i++) {
            float4 v4;
            v4.x = fmaf(o[i*4+0], z, v_s[t * 33 + i*4+0]);
            v4.y = fmaf(o[i*4+1], z, v_s[t * 33 + i*4+1]);
            v4.z = fmaf(o[i*4+2], z, v_s[t * 33 + i*4+2]);
            v4.w = fmaf(o[i*4+3], z, v_s[t * 33 + i*4+3]);
            dst[i] = v4;
        }
    }
}

// ---------------------------------------------------------------------------
extern "C" void kernel_launch(void* const* d_in, const int* in_sizes, int n_in,
                              void* d_out, int out_size, void* d_ws, size_t ws_size,
                              hipStream_t stream) {
    const float* qkv   = (const float*)d_in[0];
    const float* pos   = (const float*)d_in[1];
    const float* scale = (const float*)d_in[2];
    const float* w_v   = (const float*)d_in[3];
    const float* b_v   = (const float*)d_in[4];
    const float* w_dwc = (const float*)d_in[5];
    const float* b_dwc = (const float*)d_in[6];
    float* out = (float*)d_out;

    float* qs_arr  = (float*)d_ws;                   // B*N floats
    float* kv_ws   = qs_arr + (size_t)B_ * N_;       // 64*1024 floats
    float* ksum_ws = kv_ws + 64 * 1024;              // 64*32 floats

    (void)hipMemsetAsync(kv_ws, 0, (64 * 1024 + 64 * 32) * sizeof(float), stream);
    kernelNB<<<dim3(512), 256, 0, stream>>>(qkv, pos, scale, qs_arr, kv_ws, ksum_ws);
    kernelCD2<<<dim3(16, NH_, B_), 256, 0, stream>>>(qkv, qs_arr, kv_ws, ksum_ws,
                                                     scale, w_v, b_v, w_dwc, b_dwc, out);
}